// Round 7
// baseline (307.651 us; speedup 1.0000x reference)
//
#include <hip/hip_runtime.h>

// PersonaGNN: 2-layer GAT, N=100000, E=600000 (+self loops), dims 128, fp32 io.
//
// R7:
//  - gemm_mfma v5: prefab fragment-ordered Wf staged into LDS once per block
//    (straight 32KB memcpy, conflict-free), frags via ds_read_b128.
//    (R6 failure: every wave re-read 32KB of W-frags from L2 -> 800MB/GEMM.)
//  - gat_agg2 v3: 2 nodes per quad (8 per wave) -> two independent
//    phase-1 latency chains interleaved, half the per-wave fixed cost.
//  - CSR build / prep_w / finalize unchanged.

#define NEG_SLOPE 0.2f

typedef __attribute__((ext_vector_type(8))) short bf16x8;
typedef __attribute__((ext_vector_type(4))) float f32x4;

__device__ __forceinline__ float leaky(float x) { return x > 0.0f ? x : NEG_SLOPE * x; }

__device__ __forceinline__ unsigned int bf16rne(float f) {
  unsigned int u = __float_as_uint(f);
  return (u + 0x7fffu + ((u >> 16) & 1u)) >> 16;
}
__device__ __forceinline__ unsigned int packbf(float a, float b) {
  return bf16rne(a) | (bf16rne(b) << 16);
}
__device__ __forceinline__ float bf_lo(unsigned int u) { return __uint_as_float(u << 16); }
__device__ __forceinline__ float bf_hi(unsigned int u) { return __uint_as_float(u & 0xffff0000u); }

__device__ __forceinline__ void accum8(float* a, float w, uint4 h) {
  a[0] += w * bf_lo(h.x); a[1] += w * bf_hi(h.x);
  a[2] += w * bf_lo(h.y); a[3] += w * bf_hi(h.y);
  a[4] += w * bf_lo(h.z); a[5] += w * bf_hi(h.z);
  a[6] += w * bf_lo(h.w); a[7] += w * bf_hi(h.w);
}

// ---------------- CSR build ----------------
__global__ void hist_kernel(const int* __restrict__ dst, int* __restrict__ deg, int E) {
  int e = blockIdx.x * 256 + threadIdx.x;
  if (e < E) atomicAdd(&deg[dst[e]], 1);
}

__global__ void scan_a(const int* __restrict__ cnt, int* __restrict__ exc,
                       int* __restrict__ bsum, int n) {
  __shared__ int sh[256];
  int b = blockIdx.x, tid = threadIdx.x;
  int base = b * 1024 + tid * 4;
  int v[4];
#pragma unroll
  for (int i = 0; i < 4; i++) v[i] = (base + i < n) ? cnt[base + i] : 0;
  int tsum = v[0] + v[1] + v[2] + v[3];
  sh[tid] = tsum;
  __syncthreads();
  for (int o = 1; o < 256; o <<= 1) {
    int t = (tid >= o) ? sh[tid - o] : 0;
    __syncthreads();
    sh[tid] += t;
    __syncthreads();
  }
  if (tid == 255) bsum[b] = sh[255];
  int run = sh[tid] - tsum;
#pragma unroll
  for (int i = 0; i < 4; i++) {
    if (base + i < n) exc[base + i] = run;
    run += v[i];
  }
}

__global__ void scan_c2(const int* __restrict__ exc, const int* __restrict__ bsum,
                        int* __restrict__ rowst, int* __restrict__ fill, int n, int E,
                        int nb) {
  __shared__ int red[256];
  int b = blockIdx.x, tid = threadIdx.x;
  red[tid] = (tid < b && tid < nb) ? bsum[tid] : 0;
  __syncthreads();
#pragma unroll
  for (int o = 128; o; o >>= 1) {
    if (tid < o) red[tid] += red[tid + o];
    __syncthreads();
  }
  int off = red[0];
  int base = b * 1024 + tid * 4;
#pragma unroll
  for (int i = 0; i < 4; i++) {
    int idx = base + i;
    if (idx < n) {
      int v = exc[idx] + off;
      rowst[idx] = v;
      fill[idx] = v;
    }
  }
  if (b == 0 && tid == 0) rowst[n] = E;
}

__global__ void scatter_kernel(const int* __restrict__ src, const int* __restrict__ dst,
                               int* __restrict__ fill, int* __restrict__ esrc, int E) {
  int e = blockIdx.x * 256 + threadIdx.x;
  if (e < E) {
    int v = dst[e];
    int p = atomicAdd(&fill[v], 1);
    esrc[p] = src[e];
  }
}

// -------- prep_w: pack W (fp32 [k][n]) into fragment-ordered bf16 ----------
// Wf[fid*512 + lane*8 + j] = bf16(W[ks*32 + (lane>>4)*8 + j][ct*16 + (lane&15)]),
// fid = ct*4+ks.
__global__ void prep_w(const float* __restrict__ W1, const float* __restrict__ W2,
                       unsigned short* __restrict__ Wf1, unsigned short* __restrict__ Wf2) {
  const float* W = blockIdx.x ? W2 : W1;
  unsigned short* Wf = blockIdx.x ? Wf2 : Wf1;
  for (int idx = threadIdx.x; idx < 16384; idx += 256) {
    int j = idx & 7;
    int lane = (idx >> 3) & 63;
    int fid = idx >> 9;
    int ct = fid >> 2, ks = fid & 3;
    int q = lane >> 4, l15 = lane & 15;
    Wf[idx] = (unsigned short)bf16rne(W[(ks * 32 + q * 8 + j) * 128 + ct * 16 + l15]);
  }
}

// ------- MFMA GEMM v5: H[n,128](bf16) = X[n,128] @ W, + fused dots ----------
// Wf staged to LDS once per block; frags via ds_read_b128. One 16-row tile/wave.
template <bool F32IN>
__global__ __launch_bounds__(256) void gemm_mfma(const void* __restrict__ Xin,
                                                 const unsigned short* __restrict__ Wf,
                                                 const float* __restrict__ a_s,
                                                 const float* __restrict__ a_d,
                                                 unsigned short* __restrict__ H,
                                                 float* __restrict__ vas,
                                                 float* __restrict__ vad, int n,
                                                 int nt16) {
  __shared__ unsigned short WL[32 * 512];  // 32 KB, same layout as Wf
  const int lane = threadIdx.x & 63;
  const int wv = threadIdx.x >> 6;
  const int l15 = lane & 15;
  const int q = lane >> 4;
  const int t = blockIdx.x * 4 + wv;
  const bool wact = t < nt16;
  const int myrow = t * 16 + l15;
  const bool act = wact && (myrow < n);

  // ---- issue X loads (raw) before staging so both fly together ----
  float4 rawf[8];
  bf16x8 rawb[4];
  if (wact) {
    if constexpr (F32IN) {
      const float* __restrict__ Xf = (const float*)Xin;
#pragma unroll
      for (int ks = 0; ks < 4; ks++) {
        float4 z = {0.f, 0.f, 0.f, 0.f};
        rawf[2 * ks] = z;
        rawf[2 * ks + 1] = z;
        if (act) {
          rawf[2 * ks] = *(const float4*)&Xf[(size_t)myrow * 128 + ks * 32 + q * 8];
          rawf[2 * ks + 1] = *(const float4*)&Xf[(size_t)myrow * 128 + ks * 32 + q * 8 + 4];
        }
      }
    } else {
      const unsigned short* __restrict__ Xh = (const unsigned short*)Xin;  // padded rows
#pragma unroll
      for (int ks = 0; ks < 4; ks++)
        rawb[ks] = *(const bf16x8*)&Xh[(size_t)myrow * 128 + ks * 32 + q * 8];
    }
  }

  // ---- stage Wf -> LDS (straight copy, 8 x uint4 per thread) ----
  {
    const uint4* __restrict__ Wg4 = (const uint4*)Wf;
    uint4* WL4 = (uint4*)WL;
#pragma unroll
    for (int j = 0; j < 8; j++) WL4[threadIdx.x + 256 * j] = Wg4[threadIdx.x + 256 * j];
  }
  __syncthreads();
  if (!wact) return;

  // ---- convert X to frags ----
  bf16x8 xf[4];
  if constexpr (F32IN) {
#pragma unroll
    for (int ks = 0; ks < 4; ks++) {
      union { bf16x8 v; unsigned int u[4]; } cv;
      cv.u[0] = packbf(rawf[2 * ks].x, rawf[2 * ks].y);
      cv.u[1] = packbf(rawf[2 * ks].z, rawf[2 * ks].w);
      cv.u[2] = packbf(rawf[2 * ks + 1].x, rawf[2 * ks + 1].y);
      cv.u[3] = packbf(rawf[2 * ks + 1].z, rawf[2 * ks + 1].w);
      xf[ks] = cv.v;
    }
  } else {
#pragma unroll
    for (int ks = 0; ks < 4; ks++) xf[ks] = rawb[ks];
  }

  f32x4 acc[8];
#pragma unroll
  for (int ct = 0; ct < 8; ct++) acc[ct] = (f32x4){0.f, 0.f, 0.f, 0.f};

#pragma unroll
  for (int ks = 0; ks < 4; ks++) {
    bf16x8 wf[8];
#pragma unroll
    for (int ct = 0; ct < 8; ct++)
      wf[ct] = *(const bf16x8*)&WL[(((ct << 2) + ks) << 9) + lane * 8];
#pragma unroll
    for (int ct = 0; ct < 8; ct++)
      acc[ct] = __builtin_amdgcn_mfma_f32_16x16x32_bf16(wf[ct], xf[ks], acc[ct], 0, 0, 0);
  }

  // ---- epilogue: lane holds H[myrow][ct*16 + q*4 + r], r=0..3 ----
  float ds = 0.f, dd = 0.f;
#pragma unroll
  for (int ct = 0; ct < 8; ct++) {
    const int c0 = ct * 16 + q * 4;
    float4 as4 = *(const float4*)&a_s[c0];
    float4 ad4 = *(const float4*)&a_d[c0];
    ds += acc[ct][0] * as4.x + acc[ct][1] * as4.y + acc[ct][2] * as4.z + acc[ct][3] * as4.w;
    dd += acc[ct][0] * ad4.x + acc[ct][1] * ad4.y + acc[ct][2] * ad4.z + acc[ct][3] * ad4.w;
    if (act) {
      uint2 o;
      o.x = packbf(acc[ct][0], acc[ct][1]);
      o.y = packbf(acc[ct][2], acc[ct][3]);
      *(uint2*)&H[(size_t)myrow * 128 + c0] = o;
    }
  }
  ds += __shfl_xor(ds, 16, 64);
  ds += __shfl_xor(ds, 32, 64);
  dd += __shfl_xor(dd, 16, 64);
  dd += __shfl_xor(dd, 32, 64);
  if (q == 0 && act) {
    vas[myrow] = ds;
    vad[myrow] = dd;
  }
}

// ---- generic (deg>16, rare) per-node aggregation helper ----
__device__ __forceinline__ void agg_generic(const uint4* __restrict__ H4,
                                            const float* __restrict__ vas,
                                            const int* __restrict__ esrc, int s, int deg,
                                            float adv, float eself, int l, int lanebase,
                                            float* acc, float& wself, float& dsum) {
  float m = eself;
  for (int t0 = 0; t0 < deg; t0 += 16) {
    int j = t0 + l;
    if (j < deg) m = fmaxf(m, leaky(vas[esrc[s + j]] + adv));
  }
#pragma unroll
  for (int o = 8; o; o >>= 1) m = fmaxf(m, __shfl_xor(m, o, 16));
  wself = __expf(eself - m);
  float dl = 0.f;
  for (int t0 = 0; t0 < deg; t0 += 16) {
    int j = t0 + l;
    int u2 = 0;
    float w2 = 0.f;
    if (j < deg) {
      u2 = esrc[s + j];
      w2 = __expf(leaky(vas[u2] + adv) - m);
      dl += w2;
    }
    const int cnt = min(16, deg - t0);
    for (int i0 = 0; i0 < cnt; i0 += 8) {
      const int tb = cnt - i0;
      uint4 hb[8];
      float wt[8];
#pragma unroll
      for (int i = 0; i < 8; i++) {
        if (i < tb) {
          int ut = __shfl(u2, lanebase + i0 + i, 64);
          wt[i] = __shfl(w2, lanebase + i0 + i, 64);
          hb[i] = H4[(size_t)ut * 16 + l];
        }
      }
#pragma unroll
      for (int i = 0; i < 8; i++)
        if (i < tb) accum8(acc, wt[i], hb[i]);
    }
  }
  dsum = dl;
#pragma unroll
  for (int o = 8; o; o >>= 1) dsum += __shfl_xor(dsum, o, 16);
}

// ------------- GAT aggregation v3: 2 nodes per quad (8 per wave) -------------
// LAYER==1: relu + bf16 node output.  LAYER==2: fused mean into partial[64][128].
template <int LAYER>
__global__ __launch_bounds__(256, 4) void gat_agg2(const unsigned short* __restrict__ H,
                                                   const float* __restrict__ vas,
                                                   const float* __restrict__ vad,
                                                   const int* __restrict__ rowst,
                                                   const int* __restrict__ esrc,
                                                   const float* __restrict__ bias,
                                                   unsigned short* __restrict__ OutBf,
                                                   float* __restrict__ partial, int n) {
  const int tid = threadIdx.x;
  const int lane = tid & 63;
  const int wv = tid >> 6;
  const int q = lane >> 4;
  const int l = lane & 15;
  const int lanebase = lane & 48;
  const int n0 = (blockIdx.x * 4 + wv) * 8 + q * 2;  // 32 nodes per block
  const int n1 = n0 + 1;
  const bool act0 = n0 < n;
  const bool act1 = n1 < n;
  const uint4* __restrict__ H4 = (const uint4*)H;

  float acc0[8], acc1[8];
#pragma unroll
  for (int k = 0; k < 8; k++) { acc0[k] = 0.f; acc1[k] = 0.f; }

  if (act0) {
    // ---- phase 1 for both nodes: independent latency chains ----
    const int rb = n0;  // act0 => n0 <= n-1; rowst has n+1 entries
    const int s0 = rowst[rb];
    const int e0 = rowst[rb + 1];
    const int e1raw = rowst[min(rb + 2, n)];
    const int s1 = e0;
    const int e1 = act1 ? e1raw : e0;  // deg1=0 if node1 inactive
    const int deg0 = e0 - s0;
    const int deg1 = e1 - s1;
    const int n1c = act1 ? n1 : n0;

    const float adv0 = vad[n0], adv1 = vad[n1c];
    const float es0 = leaky(vas[n0] + adv0);
    const float es1 = leaky(vas[n1c] + adv1);
    uint4 hs0 = H4[(size_t)n0 * 16 + l];
    uint4 hs1 = H4[(size_t)n1c * 16 + l];
    float wself0, dsum0, wself1, dsum1;

    if (deg0 <= 16 && deg1 <= 16) {
      int uj0 = 0, uj1 = 0;
      float ej0 = -1e30f, ej1 = -1e30f;
      const bool a0 = l < deg0;
      const bool a1 = l < deg1;
      if (a0) { uj0 = esrc[s0 + l]; }
      if (a1) { uj1 = esrc[s1 + l]; }
      if (a0) ej0 = leaky(vas[uj0] + adv0);
      if (a1) ej1 = leaky(vas[uj1] + adv1);
      float m0 = fmaxf(es0, ej0);
      float m1 = fmaxf(es1, ej1);
#pragma unroll
      for (int o = 8; o; o >>= 1) {
        m0 = fmaxf(m0, __shfl_xor(m0, o, 16));
        m1 = fmaxf(m1, __shfl_xor(m1, o, 16));
      }
      float wj0 = a0 ? __expf(ej0 - m0) : 0.f;
      float wj1 = a1 ? __expf(ej1 - m1) : 0.f;
      wself0 = __expf(es0 - m0);
      wself1 = __expf(es1 - m1);
      dsum0 = wj0;
      dsum1 = wj1;
#pragma unroll
      for (int o = 8; o; o >>= 1) {
        dsum0 += __shfl_xor(dsum0, o, 16);
        dsum1 += __shfl_xor(dsum1, o, 16);
      }
      // ---- gather loops (batched 8-deep) ----
#pragma unroll 1
      for (int t0 = 0; t0 < deg0; t0 += 8) {
        const int tb = deg0 - t0;
        uint4 hb[8];
        float wt[8];
#pragma unroll
        for (int i = 0; i < 8; i++) {
          if (i < tb) {
            int ut = __shfl(uj0, lanebase + t0 + i, 64);
            wt[i] = __shfl(wj0, lanebase + t0 + i, 64);
            hb[i] = H4[(size_t)ut * 16 + l];
          }
        }
#pragma unroll
        for (int i = 0; i < 8; i++)
          if (i < tb) accum8(acc0, wt[i], hb[i]);
      }
#pragma unroll 1
      for (int t0 = 0; t0 < deg1; t0 += 8) {
        const int tb = deg1 - t0;
        uint4 hb[8];
        float wt[8];
#pragma unroll
        for (int i = 0; i < 8; i++) {
          if (i < tb) {
            int ut = __shfl(uj1, lanebase + t0 + i, 64);
            wt[i] = __shfl(wj1, lanebase + t0 + i, 64);
            hb[i] = H4[(size_t)ut * 16 + l];
          }
        }
#pragma unroll
        for (int i = 0; i < 8; i++)
          if (i < tb) accum8(acc1, wt[i], hb[i]);
      }
    } else {
      agg_generic(H4, vas, esrc, s0, deg0, adv0, es0, l, lanebase, acc0, wself0, dsum0);
      agg_generic(H4, vas, esrc, s1, deg1, adv1, es1, l, lanebase, acc1, wself1, dsum1);
    }

    // ---- self + normalize + bias ----
    accum8(acc0, wself0, hs0);
    accum8(acc1, wself1, hs1);
    const float inv0 = 1.0f / (dsum0 + wself0);
    const float inv1 = 1.0f / (dsum1 + wself1);
    float4 b0 = *(const float4*)&bias[8 * l];
    float4 b1v = *(const float4*)&bias[8 * l + 4];
    const float bb[8] = {b0.x, b0.y, b0.z, b0.w, b1v.x, b1v.y, b1v.z, b1v.w};
#pragma unroll
    for (int k = 0; k < 8; k++) {
      acc0[k] = acc0[k] * inv0 + bb[k];
      acc1[k] = acc1[k] * inv1 + bb[k];
    }

    if (LAYER == 1) {
#pragma unroll
      for (int k = 0; k < 8; k++) {
        acc0[k] = fmaxf(acc0[k], 0.f);
        acc1[k] = fmaxf(acc1[k], 0.f);
      }
      uint4 o0, o1;
      o0.x = packbf(acc0[0], acc0[1]); o0.y = packbf(acc0[2], acc0[3]);
      o0.z = packbf(acc0[4], acc0[5]); o0.w = packbf(acc0[6], acc0[7]);
      ((uint4*)OutBf)[(size_t)n0 * 16 + l] = o0;
      if (act1) {
        o1.x = packbf(acc1[0], acc1[1]); o1.y = packbf(acc1[2], acc1[3]);
        o1.z = packbf(acc1[4], acc1[5]); o1.w = packbf(acc1[6], acc1[7]);
        ((uint4*)OutBf)[(size_t)n1 * 16 + l] = o1;
      }
    }
    if (LAYER == 2 && !act1) {
#pragma unroll
      for (int k = 0; k < 8; k++) acc1[k] = 0.f;
    }
  }

  if (LAYER == 2) {
    float accs[8];
#pragma unroll
    for (int k = 0; k < 8; k++) {
      accs[k] = acc0[k] + acc1[k];
      accs[k] += __shfl_xor(accs[k], 16, 64);
      accs[k] += __shfl_xor(accs[k], 32, 64);
    }
    __shared__ float red[4][128];
    if (q == 0) {
#pragma unroll
      for (int k = 0; k < 8; k++) red[wv][8 * l + k] = accs[k];
    }
    __syncthreads();
    if (tid < 128) {
      float sm = red[0][tid] + red[1][tid] + red[2][tid] + red[3][tid];
      atomicAdd(&partial[(blockIdx.x & 63) * 128 + tid], sm);
    }
  }
}

// ---------------- finalize: out = sum(partial)/N ----------------
__global__ void finalize_k(const float* __restrict__ partial, float* __restrict__ out,
                           float invn) {
  int c = threadIdx.x;  // 128
  float s = 0.f;
#pragma unroll 8
  for (int r = 0; r < 64; r++) s += partial[r * 128 + c];
  out[c] = s * invn;
}

extern "C" void kernel_launch(void* const* d_in, const int* in_sizes, int n_in,
                              void* d_out, int out_size, void* d_ws, size_t ws_size,
                              hipStream_t stream) {
  const float* x = (const float*)d_in[0];
  const int* ei = (const int*)d_in[1];
  const float* W1 = (const float*)d_in[2];
  const float* a_src1 = (const float*)d_in[3];
  const float* a_dst1 = (const float*)d_in[4];
  const float* b1 = (const float*)d_in[5];
  const float* W2 = (const float*)d_in[6];
  const float* a_src2 = (const float*)d_in[7];
  const float* a_dst2 = (const float*)d_in[8];
  const float* b2 = (const float*)d_in[9];
  float* out = (float*)d_out;

  const int N = in_sizes[0] / 128;
  const int E = in_sizes[1] / 2;
  const int* src = ei;
  const int* dst = ei + E;

  const size_t rowpadded = (size_t)(N + 64) * 128;

  char* p = (char*)d_ws;
  unsigned short* B1h = (unsigned short*)p; p += rowpadded * 2;  // layer-1 agg out (bf16)
  unsigned short* Hh = (unsigned short*)p;  p += rowpadded * 2;  // per-layer GEMM out (bf16)
  float* vas = (float*)p;     p += (size_t)N * 4;
  float* vad = (float*)p;     p += (size_t)N * 4;
  int* deg = (int*)p;         p += (size_t)N * 4;
  int* rowst = (int*)p;       p += (size_t)(N + 1) * 4;
  int* fill = (int*)p;        p += (size_t)N * 4;
  int* esrc = (int*)p;        p += (size_t)E * 4;
  int* exc = (int*)p;         p += (size_t)N * 4;
  int* bsum = (int*)p;        p += 256 * 4;
  float* partial = (float*)p; p += 64 * 128 * 4;
  unsigned short* Wf1 = (unsigned short*)p; p += 16384 * 2;
  unsigned short* Wf2 = (unsigned short*)p; p += 16384 * 2;

  const int nb = (N + 1023) / 1024;  // 98 (<=128 required by scan_c2 reduce)
  const int eblocks = (E + 255) / 256;
  const int nt16 = (N + 15) / 16;
  const int gemmblocks = (nt16 + 3) / 4;  // 1 tile per wave
  const int aggblocks = (N + 31) / 32;    // 32 nodes per 256-thread block

  // --- CSR over dst + W prep ---
  hipMemsetAsync(deg, 0, (size_t)N * 4, stream);
  prep_w<<<2, 256, 0, stream>>>(W1, W2, Wf1, Wf2);
  hist_kernel<<<eblocks, 256, 0, stream>>>(dst, deg, E);
  scan_a<<<nb, 256, 0, stream>>>(deg, exc, bsum, N);
  scan_c2<<<nb, 256, 0, stream>>>(exc, bsum, rowst, fill, N, E, nb);
  scatter_kernel<<<eblocks, 256, 0, stream>>>(src, dst, fill, esrc, E);

  // --- layer 1 (fp32 x read directly) ---
  gemm_mfma<true><<<gemmblocks, 256, 0, stream>>>(x, Wf1, a_src1, a_dst1, Hh, vas, vad, N, nt16);
  gat_agg2<1><<<aggblocks, 256, 0, stream>>>(Hh, vas, vad, rowst, esrc, b1, B1h, nullptr, N);

  // --- layer 2 (fused mean) ---
  gemm_mfma<false><<<gemmblocks, 256, 0, stream>>>(B1h, Wf2, a_src2, a_dst2, Hh, vas, vad, N, nt16);
  hipMemsetAsync(partial, 0, 64 * 128 * 4, stream);
  gat_agg2<2><<<aggblocks, 256, 0, stream>>>(Hh, vas, vad, rowst, esrc, b2, nullptr, partial, N);

  // --- finalize mean ---
  finalize_k<<<1, 128, 0, stream>>>(partial, out, 1.0f / (float)N);
}